// Round 16
// baseline (2114.558 us; speedup 1.0000x reference)
//
#include <hip/hip_runtime.h>

#define NN 100000
#define NE 3200000
#define EB 4096            // edges per partition block
#define NBP 782            // ceil(NE/EB)
#define BSH 7              // bucket = row >> 7
#define BRW 128            // rows per bucket
#define NBK 782            // ceil(NN/BRW)
#define NBK2 784           // padded even
#define CAP 4608           // fixed bucket window (mean 4096, +8 sigma)

typedef short short8 __attribute__((ext_vector_type(8)));
typedef float f32x4 __attribute__((ext_vector_type(4)));

static __device__ __forceinline__ unsigned short f2bf(float f) {
  union { float f; unsigned int u; } c; c.f = f;
  unsigned int r = c.u + 0x7FFFu + ((c.u >> 16) & 1u);
  return (unsigned short)(r >> 16);
}
static __device__ __forceinline__ float lo16(unsigned int w) {
  union { unsigned int u; float f; } c; c.u = w << 16; return c.f;
}
static __device__ __forceinline__ float hi16(unsigned int w) {
  union { unsigned int u; float f; } c; c.u = w & 0xFFFF0000u; return c.f;
}

// ---------------- CSR build: fixed-window bucket partition (no row sort!) ----------------

__global__ __launch_bounds__(256) void k_binit(int* __restrict__ bcur) {
  int t = blockIdx.x * 256 + threadIdx.x;
  if (t < NBK) bcur[t] = t * CAP;
}

// partition edges into fixed bucket windows of tmp[]
__global__ __launch_bounds__(512) void k_part(const int* __restrict__ row,
                                              const int* __restrict__ col,
                                              const float* __restrict__ val,
                                              int* __restrict__ bcur,
                                              uint2* __restrict__ tmp) {
  __shared__ uint2 stage[EB];   // 32 KB
  __shared__ int dst[EB];       // 16 KB
  __shared__ int h[NBK2];
  __shared__ int bex[NBK2];
  __shared__ int win[NBK2];
  __shared__ int c2[NBK2];
  __shared__ int sc[512];
  int t = threadIdx.x;
  int e0 = blockIdx.x * EB;
  int n = min(EB, NE - e0);
  for (int k = t; k < NBK2; k += 512) { h[k] = 0; c2[k] = 0; }
  __syncthreads();
  for (int i = t; i < n; i += 512) atomicAdd(&h[row[e0 + i] >> BSH], 1);
  __syncthreads();
  int k0 = 2 * t, k1 = 2 * t + 1;
  int v0 = (t < 392) ? h[k0] : 0;
  int v1 = (t < 392) ? h[k1] : 0;
  int s = v0 + v1;
  sc[t] = s;
  __syncthreads();
  for (int off = 1; off < 512; off <<= 1) {
    int a = (t >= off) ? sc[t - off] : 0;
    __syncthreads();
    sc[t] += a;
    __syncthreads();
  }
  int ex = sc[t] - s;
  if (t < 392) {
    bex[k0] = ex;
    bex[k1] = ex + v0;
    win[k0] = v0 ? atomicAdd(&bcur[k0], v0) : 0;
    win[k1] = v1 ? atomicAdd(&bcur[k1], v1) : 0;
  }
  __syncthreads();
  for (int i = t; i < n; i += 512) {
    int e = e0 + i;
    int r = row[e];
    unsigned int c = (unsigned int)col[e];
    float vv = val[e];
    int b = r >> BSH;
    int rank = atomicAdd(&c2[b], 1);
    int s_ = bex[b] + rank;
    uint2 w;
    w.x = __float_as_uint(vv);
    w.y = ((unsigned int)(r & (BRW - 1)) << 17) | c;
    stage[s_] = w;
    dst[s_] = win[b] + rank;
  }
  __syncthreads();
  for (int i = t; i < n; i += 512) tmp[dst[i]] = stage[i];
}

// ---------------- weight conversion (both layers, parallel) ----------------
__global__ __launch_bounds__(256) void k_wcvt(const float* __restrict__ W0,
                                              unsigned short* __restrict__ W0bT,
                                              const float* __restrict__ W1,
                                              unsigned short* __restrict__ W1bT) {
  int idx = blockIdx.x * 256 + threadIdx.x;
  if (idx < 8192) {
    int n = idx >> 7, k = idx & 127;
    W0bT[idx] = f2bf(W0[(size_t)k * 64 + n]);
  } else if (idx < 8192 + 2048) {
    int i2 = idx - 8192;
    int n = i2 >> 6, k = i2 & 63;
    W1bT[i2] = f2bf(W1[(size_t)k * 32 + n]);
  }
}

// ---------------- dense layer 0: MFMA bf16 ----------------

__global__ __launch_bounds__(256) void k_gemm0(const float* __restrict__ x,
                                               const float* __restrict__ u,
                                               const unsigned short* __restrict__ W0bT,
                                               const float* __restrict__ b0,
                                               unsigned short* __restrict__ h0b) {
  __shared__ unsigned short xs[64][136];   // bf16 rows, pad 8
  int t = threadIdx.x;
  int r0 = blockIdx.x * 64;
#pragma unroll
  for (int i = 0; i < 8; ++i) {
    int f4 = t + i * 256;
    int row = f4 >> 5;
    int off = f4 & 31;
    int r = r0 + row;
    float4 m = make_float4(0.f, 0.f, 0.f, 0.f);
    if (r < NN) {
      float4 xv = ((const float4*)(x + (size_t)r * 128))[off];
      float4 uv = ((const float4*)(u + (size_t)r * 128))[off];
      m.x = (uv.x >= 0.5f) ? xv.x : 0.f;
      m.y = (uv.y >= 0.5f) ? xv.y : 0.f;
      m.z = (uv.z >= 0.5f) ? xv.z : 0.f;
      m.w = (uv.w >= 0.5f) ? xv.w : 0.f;
    }
    uint2 pk;
    pk.x = (unsigned int)f2bf(m.x) | ((unsigned int)f2bf(m.y) << 16);
    pk.y = (unsigned int)f2bf(m.z) | ((unsigned int)f2bf(m.w) << 16);
    *(uint2*)&xs[row][off * 4] = pk;
  }
  __syncthreads();

  int lane = t & 63;
  int wv = __builtin_amdgcn_readfirstlane(t >> 6);
  int arow = wv * 16 + (lane & 15);
  int kgrp = lane >> 4;
  int ncol = lane & 15;

  short8 afrag[4];
#pragma unroll
  for (int kb = 0; kb < 4; ++kb)
    afrag[kb] = *(const short8*)&xs[arow][kgrp * 8 + kb * 32];

  short8 bfrag[4][4];
#pragma unroll
  for (int kb = 0; kb < 4; ++kb)
#pragma unroll
    for (int nb = 0; nb < 4; ++nb)
      bfrag[kb][nb] = *(const short8*)&W0bT[(size_t)(nb * 16 + ncol) * 128 +
                                            kgrp * 8 + kb * 32];

  f32x4 acc[4];
#pragma unroll
  for (int nb = 0; nb < 4; ++nb) acc[nb] = (f32x4)(0.f);
#pragma unroll
  for (int kb = 0; kb < 4; ++kb)
#pragma unroll
    for (int nb = 0; nb < 4; ++nb)
      acc[nb] = __builtin_amdgcn_mfma_f32_16x16x32_bf16(afrag[kb], bfrag[kb][nb],
                                                        acc[nb], 0, 0, 0);

#pragma unroll
  for (int nb = 0; nb < 4; ++nb) {
    int c = nb * 16 + ncol;
    float bias = b0[c];
#pragma unroll
    for (int reg = 0; reg < 4; ++reg) {
      int rr = r0 + wv * 16 + kgrp * 4 + reg;
      if (rr < NN) h0b[(size_t)rr * 64 + c] = f2bf(2.f * acc[nb][reg] + bias);
    }
  }
}

// ---------------- dense layer 1: MFMA bf16 (K=64, N=32) ----------------

__global__ __launch_bounds__(256) void k_gemm1(const unsigned short* __restrict__ s1b,
                                               const unsigned short* __restrict__ W1bT,
                                               const float* __restrict__ b1,
                                               unsigned short* __restrict__ h1b) {
  __shared__ unsigned short ss[64][72];   // 64 rows x 64 bf16, pad 8
  int t = threadIdx.x;
  int r0 = blockIdx.x * 64;
#pragma unroll
  for (int i = 0; i < 2; ++i) {
    int q = t + i * 256;
    int row = q >> 3;
    int off = q & 7;
    int r = r0 + row;
    uint4 w = make_uint4(0u, 0u, 0u, 0u);
    if (r < NN) w = ((const uint4*)(s1b + (size_t)r * 64))[off];
    *(uint4*)&ss[row][off * 8] = w;
  }
  __syncthreads();

  int lane = t & 63;
  int wv = __builtin_amdgcn_readfirstlane(t >> 6);
  int arow = wv * 16 + (lane & 15);
  int kgrp = lane >> 4;
  int ncol = lane & 15;

  short8 afrag[2];
#pragma unroll
  for (int kb = 0; kb < 2; ++kb)
    afrag[kb] = *(const short8*)&ss[arow][kgrp * 8 + kb * 32];

  short8 bfrag[2][2];
#pragma unroll
  for (int kb = 0; kb < 2; ++kb)
#pragma unroll
    for (int nb = 0; nb < 2; ++nb)
      bfrag[kb][nb] = *(const short8*)&W1bT[(size_t)(nb * 16 + ncol) * 64 +
                                            kgrp * 8 + kb * 32];

  f32x4 acc[2];
#pragma unroll
  for (int nb = 0; nb < 2; ++nb) acc[nb] = (f32x4)(0.f);
#pragma unroll
  for (int kb = 0; kb < 2; ++kb)
#pragma unroll
    for (int nb = 0; nb < 2; ++nb)
      acc[nb] = __builtin_amdgcn_mfma_f32_16x16x32_bf16(afrag[kb], bfrag[kb][nb],
                                                        acc[nb], 0, 0, 0);

#pragma unroll
  for (int nb = 0; nb < 2; ++nb) {
    int c = nb * 16 + ncol;
    float bias = b1[c];
#pragma unroll
    for (int reg = 0; reg < 4; ++reg) {
      int rr = r0 + wv * 16 + kgrp * 4 + reg;
      if (rr < NN) h1b[(size_t)rr * 32 + c] = f2bf(acc[nb][reg] + bias);
    }
  }
}

// ---------------- SpMM: bucket-direct, LDS fp32 accumulator, no row sort ----------------

// D=64: block = 1 bucket (128 rows). Wave handles 8 unsorted edges/iter
// (4 slots x 2), records prefetched one chunk ahead; ds atomics into acc.
__global__ __launch_bounds__(512) void k_spmm1(const int* __restrict__ bcur,
                                               const uint2* __restrict__ tmp,
                                               const uint2* __restrict__ h0v,
                                               uint2* __restrict__ s1v) {
  __shared__ float acc[128][65];   // 33.3 KB, +1 pad (rl*64 is bank-aliased)
  int t = threadIdx.x;
  int b = blockIdx.x;
  int s0 = b * CAP;
  int s1e = bcur[b];
  for (int i = t; i < 128 * 65; i += 512) ((float*)acc)[i] = 0.f;
  __syncthreads();

  int w = t >> 6, lane = t & 63;
  int sl = lane >> 4;        // edge slot 0..3
  int d = lane & 15;         // uint2 index: dims 4d..4d+3
  int base = s0 + w * 8;
  uint2 eA, eB;
  bool full = (base + 8 <= s1e);
  if (full) { eA = tmp[base + sl]; eB = tmp[base + sl + 4]; }
  while (full) {
    uint2 gA = h0v[(size_t)(eA.y & 0x1FFFFu) * 16 + d];
    uint2 gB = h0v[(size_t)(eB.y & 0x1FFFFu) * 16 + d];
    float vA = __uint_as_float(eA.x);
    float vB = __uint_as_float(eB.x);
    int rlA = (int)(eA.y >> 17), rlB = (int)(eB.y >> 17);
    int nb = base + 64;
    bool nf = (nb + 8 <= s1e);
    if (nf) { eA = tmp[nb + sl]; eB = tmp[nb + sl + 4]; }
    atomicAdd(&acc[rlA][4 * d + 0], vA * lo16(gA.x));
    atomicAdd(&acc[rlA][4 * d + 1], vA * hi16(gA.x));
    atomicAdd(&acc[rlA][4 * d + 2], vA * lo16(gA.y));
    atomicAdd(&acc[rlA][4 * d + 3], vA * hi16(gA.y));
    atomicAdd(&acc[rlB][4 * d + 0], vB * lo16(gB.x));
    atomicAdd(&acc[rlB][4 * d + 1], vB * hi16(gB.x));
    atomicAdd(&acc[rlB][4 * d + 2], vB * lo16(gB.y));
    atomicAdd(&acc[rlB][4 * d + 3], vB * hi16(gB.y));
    base = nb; full = nf;
  }
  if (base < s1e) {   // tail chunk (<8 edges for this wave)
    int jA = base + sl, jB = base + sl + 4;
    bool okA = jA < s1e, okB = jB < s1e;
    uint2 tA = okA ? tmp[jA] : make_uint2(0u, 0u);
    uint2 tB = okB ? tmp[jB] : make_uint2(0u, 0u);
    uint2 gA = h0v[(size_t)(tA.y & 0x1FFFFu) * 16 + d];
    uint2 gB = h0v[(size_t)(tB.y & 0x1FFFFu) * 16 + d];
    float vA = okA ? __uint_as_float(tA.x) : 0.f;
    float vB = okB ? __uint_as_float(tB.x) : 0.f;
    int rlA = (int)(tA.y >> 17), rlB = (int)(tB.y >> 17);
    atomicAdd(&acc[rlA][4 * d + 0], vA * lo16(gA.x));
    atomicAdd(&acc[rlA][4 * d + 1], vA * hi16(gA.x));
    atomicAdd(&acc[rlA][4 * d + 2], vA * lo16(gA.y));
    atomicAdd(&acc[rlA][4 * d + 3], vA * hi16(gA.y));
    atomicAdd(&acc[rlB][4 * d + 0], vB * lo16(gB.x));
    atomicAdd(&acc[rlB][4 * d + 1], vB * hi16(gB.x));
    atomicAdd(&acc[rlB][4 * d + 2], vB * lo16(gB.y));
    atomicAdd(&acc[rlB][4 * d + 3], vB * hi16(gB.y));
  }
  __syncthreads();
  // relu + bf16 pack + coalesced store: 128 rows x 16 uint2
  int r0 = b << BSH;
  for (int i = t; i < 128 * 16; i += 512) {
    int rl = i >> 4, dd = i & 15;
    int r = r0 + rl;
    if (r < NN) {
      float f0 = fmaxf(acc[rl][4 * dd + 0], 0.f);
      float f1 = fmaxf(acc[rl][4 * dd + 1], 0.f);
      float f2 = fmaxf(acc[rl][4 * dd + 2], 0.f);
      float f3 = fmaxf(acc[rl][4 * dd + 3], 0.f);
      uint2 pk;
      pk.x = (unsigned int)f2bf(f0) | ((unsigned int)f2bf(f1) << 16);
      pk.y = (unsigned int)f2bf(f2) | ((unsigned int)f2bf(f3) << 16);
      s1v[(size_t)r * 16 + dd] = pk;
    }
  }
}

// D=32: block = 1 bucket. Wave handles 16 edges/iter (8 slots x 2).
__global__ __launch_bounds__(512) void k_spmm2(const int* __restrict__ bcur,
                                               const uint2* __restrict__ tmp,
                                               const uint2* __restrict__ h1v,
                                               float* __restrict__ out) {
  __shared__ float acc[128][33];   // 16.9 KB
  int t = threadIdx.x;
  int b = blockIdx.x;
  int s0 = b * CAP;
  int s1e = bcur[b];
  for (int i = t; i < 128 * 33; i += 512) ((float*)acc)[i] = 0.f;
  __syncthreads();

  int w = t >> 6, lane = t & 63;
  int sl = lane >> 3;        // edge slot 0..7
  int d = lane & 7;          // uint2 index: dims 4d..4d+3
  int base = s0 + w * 16;
  uint2 eA, eB;
  bool full = (base + 16 <= s1e);
  if (full) { eA = tmp[base + sl]; eB = tmp[base + sl + 8]; }
  while (full) {
    uint2 gA = h1v[(size_t)(eA.y & 0x1FFFFu) * 8 + d];
    uint2 gB = h1v[(size_t)(eB.y & 0x1FFFFu) * 8 + d];
    float vA = __uint_as_float(eA.x);
    float vB = __uint_as_float(eB.x);
    int rlA = (int)(eA.y >> 17), rlB = (int)(eB.y >> 17);
    int nb = base + 128;
    bool nf = (nb + 16 <= s1e);
    if (nf) { eA = tmp[nb + sl]; eB = tmp[nb + sl + 8]; }
    atomicAdd(&acc[rlA][4 * d + 0], vA * lo16(gA.x));
    atomicAdd(&acc[rlA][4 * d + 1], vA * hi16(gA.x));
    atomicAdd(&acc[rlA][4 * d + 2], vA * lo16(gA.y));
    atomicAdd(&acc[rlA][4 * d + 3], vA * hi16(gA.y));
    atomicAdd(&acc[rlB][4 * d + 0], vB * lo16(gB.x));
    atomicAdd(&acc[rlB][4 * d + 1], vB * hi16(gB.x));
    atomicAdd(&acc[rlB][4 * d + 2], vB * lo16(gB.y));
    atomicAdd(&acc[rlB][4 * d + 3], vB * hi16(gB.y));
    base = nb; full = nf;
  }
  if (base < s1e) {
    int jA = base + sl, jB = base + sl + 8;
    bool okA = jA < s1e, okB = jB < s1e;
    uint2 tA = okA ? tmp[jA] : make_uint2(0u, 0u);
    uint2 tB = okB ? tmp[jB] : make_uint2(0u, 0u);
    uint2 gA = h1v[(size_t)(tA.y & 0x1FFFFu) * 8 + d];
    uint2 gB = h1v[(size_t)(tB.y & 0x1FFFFu) * 8 + d];
    float vA = okA ? __uint_as_float(tA.x) : 0.f;
    float vB = okB ? __uint_as_float(tB.x) : 0.f;
    int rlA = (int)(tA.y >> 17), rlB = (int)(tB.y >> 17);
    atomicAdd(&acc[rlA][4 * d + 0], vA * lo16(gA.x));
    atomicAdd(&acc[rlA][4 * d + 1], vA * hi16(gA.x));
    atomicAdd(&acc[rlA][4 * d + 2], vA * lo16(gA.y));
    atomicAdd(&acc[rlA][4 * d + 3], vA * hi16(gA.y));
    atomicAdd(&acc[rlB][4 * d + 0], vB * lo16(gB.x));
    atomicAdd(&acc[rlB][4 * d + 1], vB * hi16(gB.x));
    atomicAdd(&acc[rlB][4 * d + 2], vB * lo16(gB.y));
    atomicAdd(&acc[rlB][4 * d + 3], vB * hi16(gB.y));
  }
  __syncthreads();
  // store: 128 rows x 8 float4
  int r0 = b << BSH;
  for (int i = t; i < 128 * 8; i += 512) {
    int rl = i >> 3, dd = i & 7;
    int r = r0 + rl;
    if (r < NN) {
      float4 o = make_float4(acc[rl][4 * dd + 0], acc[rl][4 * dd + 1],
                             acc[rl][4 * dd + 2], acc[rl][4 * dd + 3]);
      ((float4*)(out + (size_t)r * 32))[dd] = o;
    }
  }
}

// ---------------- launch ----------------

extern "C" void kernel_launch(void* const* d_in, const int* in_sizes, int n_in,
                              void* d_out, int out_size, void* d_ws, size_t ws_size,
                              hipStream_t stream) {
  const float* x   = (const float*)d_in[0];
  const float* u   = (const float*)d_in[1];
  const float* val = (const float*)d_in[2];
  const int* row   = (const int*)d_in[3];
  const int* col   = (const int*)d_in[4];
  const float* W0  = (const float*)d_in[5];
  const float* b0  = (const float*)d_in[6];
  const float* W1  = (const float*)d_in[7];
  const float* b1  = (const float*)d_in[8];
  float* out = (float*)d_out;

  char* p = (char*)d_ws;
  auto take = [&](size_t bytes) {
    char* q = p;
    p += (bytes + 255) & ~(size_t)255;
    return q;
  };
  uint2* tmp = (uint2*)take((size_t)NBK * CAP * 8);   // LIVE through spmm2
  unsigned short* h0b = (unsigned short*)take((size_t)NN * 64 * 2);
  unsigned short* h1b = (unsigned short*)take((size_t)NN * 32 * 2);
  unsigned short* s1b = (unsigned short*)take((size_t)NN * 64 * 2);
  int* bcur  = (int*)take((size_t)NBK * 4);
  unsigned short* w0bt = (unsigned short*)take((size_t)64 * 128 * 2);
  unsigned short* w1bt = (unsigned short*)take((size_t)32 * 64 * 2);

  // CSR build: bucket partition only (no row sort)
  k_binit<<<(NBK + 255) / 256, 256, 0, stream>>>(bcur);
  k_part<<<NBP, 512, 0, stream>>>(row, col, val, bcur, tmp);

  // dense + sparse pipeline
  k_wcvt<<<40, 256, 0, stream>>>(W0, w0bt, W1, w1bt);
  k_gemm0<<<(NN + 63) / 64, 256, 0, stream>>>(x, u, w0bt, b0, h0b);
  k_spmm1<<<NBK, 512, 0, stream>>>(bcur, tmp, (const uint2*)h0b, (uint2*)s1b);
  k_gemm1<<<(NN + 63) / 64, 256, 0, stream>>>(s1b, w1bt, b1, h1b);
  k_spmm2<<<NBK, 512, 0, stream>>>(bcur, tmp, (const uint2*)h1b, out);
}

// Round 17
// 215.975 us; speedup vs baseline: 9.7907x; 9.7907x over previous
//
#include <hip/hip_runtime.h>

#define NN 100000
#define NE 3200000
#define EB 4096            // edges per partition block (51 KB LDS -> 3 blocks/CU)
#define NBP 782            // ceil(NE/EB)
#define BSH 9              // bucket = row >> 9
#define BRW 512            // rows per bucket
#define NBK 196            // ceil(NN/BRW)
#define CAP 17408          // fixed bucket window (mean 16326, +8.4 sigma)

typedef short short8 __attribute__((ext_vector_type(8)));
typedef float f32x4 __attribute__((ext_vector_type(4)));

static __device__ __forceinline__ unsigned short f2bf(float f) {
  union { float f; unsigned int u; } c; c.f = f;
  unsigned int r = c.u + 0x7FFFu + ((c.u >> 16) & 1u);
  return (unsigned short)(r >> 16);
}
static __device__ __forceinline__ float lo16(unsigned int w) {
  union { unsigned int u; float f; } c; c.u = w << 16; return c.f;
}
static __device__ __forceinline__ float hi16(unsigned int w) {
  union { unsigned int u; float f; } c; c.u = w & 0xFFFF0000u; return c.f;
}

// ---------------- CSR build: fixed-window bucket sort ----------------

__global__ __launch_bounds__(256) void k_binit(int* __restrict__ bcur) {
  int t = threadIdx.x;
  if (t < NBK) bcur[t] = t * CAP;
}

// partition edges into fixed bucket windows of tmp[]
__global__ __launch_bounds__(512) void k_part(const int* __restrict__ row,
                                              const int* __restrict__ col,
                                              const float* __restrict__ val,
                                              int* __restrict__ bcur,
                                              uint2* __restrict__ tmp) {
  __shared__ uint2 stage[EB];   // 32 KB
  __shared__ int dst[EB];       // 16 KB
  __shared__ int h[NBK];
  __shared__ int bex[NBK];
  __shared__ int win[NBK];
  __shared__ int c2[NBK];
  __shared__ int sc[512];
  int t = threadIdx.x;
  int e0 = blockIdx.x * EB;
  int n = min(EB, NE - e0);
  if (t < NBK) { h[t] = 0; c2[t] = 0; }
  __syncthreads();
  for (int i = t; i < n; i += 512) atomicAdd(&h[row[e0 + i] >> BSH], 1);
  __syncthreads();
  int v = (t < NBK) ? h[t] : 0;
  sc[t] = v;
  __syncthreads();
  for (int off = 1; off < 512; off <<= 1) {
    int a = (t >= off) ? sc[t - off] : 0;
    __syncthreads();
    sc[t] += a;
    __syncthreads();
  }
  int ex = sc[t] - v;
  if (t < NBK) {
    bex[t] = ex;
    win[t] = v ? atomicAdd(&bcur[t], v) : 0;
  }
  __syncthreads();
  for (int i = t; i < n; i += 512) {
    int e = e0 + i;
    int r = row[e];
    unsigned int c = (unsigned int)col[e];
    float vv = val[e];
    int b = r >> BSH;
    int rank = atomicAdd(&c2[b], 1);
    int s_ = bex[b] + rank;
    uint2 w;
    w.x = __float_as_uint(vv);
    w.y = ((unsigned int)(r & (BRW - 1)) << 17) | c;
    stage[s_] = w;
    dst[s_] = win[b] + rank;
  }
  __syncthreads();
  for (int i = t; i < n; i += 512) tmp[dst[i]] = stage[i];
}

// per-bucket counting sort by row -> vc (fixed windows) + split row pointers
__global__ __launch_bounds__(1024) void k_bsort(const int* __restrict__ bcur,
                                                const uint2* __restrict__ tmp,
                                                uint2* __restrict__ vc,
                                                int* __restrict__ rps,
                                                int* __restrict__ rpe) {
  __shared__ int cnt[BRW];
  __shared__ int pre[BRW];
  __shared__ int c2[BRW];
  int t = threadIdx.x;
  int b = blockIdx.x;
  int s0 = b * CAP;
  int n = bcur[b] - s0;
  if (t < BRW) { cnt[t] = 0; c2[t] = 0; }
  __syncthreads();
  const unsigned int* tmpy = (const unsigned int*)tmp;
  for (int i = t; i < n; i += 1024)
    atomicAdd(&cnt[tmpy[2 * (s0 + i) + 1] >> 17], 1);
  __syncthreads();
  int v = (t < BRW) ? cnt[t] : 0;
  if (t < BRW) pre[t] = v;
  __syncthreads();
  for (int off = 1; off < BRW; off <<= 1) {
    int a = (t >= off && t < BRW) ? pre[t - off] : 0;
    __syncthreads();
    if (t < BRW) pre[t] += a;
    __syncthreads();
  }
  if (t < BRW) {
    int ex = pre[t] - v;
    int r = (b << BSH) + t;
    if (r < NN) { rps[r] = s0 + ex; rpe[r] = s0 + ex + v; }
    pre[t] = ex;
  }
  __syncthreads();
  for (int i = t; i < n; i += 1024) {
    uint2 w = tmp[s0 + i];
    int rl = (int)(w.y >> 17);
    int rank = atomicAdd(&c2[rl], 1);
    int pos = s0 + pre[rl] + rank;
    uint2 o;
    o.x = w.x;
    o.y = w.y & 0x1FFFFu;
    vc[pos] = o;
  }
}

// ---------------- weight conversion (both layers, parallel) ----------------
__global__ __launch_bounds__(256) void k_wcvt(const float* __restrict__ W0,
                                              unsigned short* __restrict__ W0bT,
                                              const float* __restrict__ W1,
                                              unsigned short* __restrict__ W1bT) {
  int idx = blockIdx.x * 256 + threadIdx.x;
  if (idx < 8192) {
    int n = idx >> 7, k = idx & 127;
    W0bT[idx] = f2bf(W0[(size_t)k * 64 + n]);
  } else if (idx < 8192 + 2048) {
    int i2 = idx - 8192;
    int n = i2 >> 6, k = i2 & 63;
    W1bT[i2] = f2bf(W1[(size_t)k * 32 + n]);
  }
}

// ---------------- dense layer 0: MFMA bf16 ----------------

__global__ __launch_bounds__(256) void k_gemm0(const float* __restrict__ x,
                                               const float* __restrict__ u,
                                               const unsigned short* __restrict__ W0bT,
                                               const float* __restrict__ b0,
                                               unsigned short* __restrict__ h0b) {
  __shared__ unsigned short xs[64][136];   // bf16 rows, pad 8
  int t = threadIdx.x;
  int r0 = blockIdx.x * 64;
#pragma unroll
  for (int i = 0; i < 8; ++i) {
    int f4 = t + i * 256;
    int row = f4 >> 5;
    int off = f4 & 31;
    int r = r0 + row;
    float4 m = make_float4(0.f, 0.f, 0.f, 0.f);
    if (r < NN) {
      float4 xv = ((const float4*)(x + (size_t)r * 128))[off];
      float4 uv = ((const float4*)(u + (size_t)r * 128))[off];
      m.x = (uv.x >= 0.5f) ? xv.x : 0.f;
      m.y = (uv.y >= 0.5f) ? xv.y : 0.f;
      m.z = (uv.z >= 0.5f) ? xv.z : 0.f;
      m.w = (uv.w >= 0.5f) ? xv.w : 0.f;
    }
    uint2 pk;
    pk.x = (unsigned int)f2bf(m.x) | ((unsigned int)f2bf(m.y) << 16);
    pk.y = (unsigned int)f2bf(m.z) | ((unsigned int)f2bf(m.w) << 16);
    *(uint2*)&xs[row][off * 4] = pk;
  }
  __syncthreads();

  int lane = t & 63;
  int wv = __builtin_amdgcn_readfirstlane(t >> 6);
  int arow = wv * 16 + (lane & 15);
  int kgrp = lane >> 4;
  int ncol = lane & 15;

  short8 afrag[4];
#pragma unroll
  for (int kb = 0; kb < 4; ++kb)
    afrag[kb] = *(const short8*)&xs[arow][kgrp * 8 + kb * 32];

  short8 bfrag[4][4];
#pragma unroll
  for (int kb = 0; kb < 4; ++kb)
#pragma unroll
    for (int nb = 0; nb < 4; ++nb)
      bfrag[kb][nb] = *(const short8*)&W0bT[(size_t)(nb * 16 + ncol) * 128 +
                                            kgrp * 8 + kb * 32];

  f32x4 acc[4];
#pragma unroll
  for (int nb = 0; nb < 4; ++nb) acc[nb] = (f32x4)(0.f);
#pragma unroll
  for (int kb = 0; kb < 4; ++kb)
#pragma unroll
    for (int nb = 0; nb < 4; ++nb)
      acc[nb] = __builtin_amdgcn_mfma_f32_16x16x32_bf16(afrag[kb], bfrag[kb][nb],
                                                        acc[nb], 0, 0, 0);

#pragma unroll
  for (int nb = 0; nb < 4; ++nb) {
    int c = nb * 16 + ncol;
    float bias = b0[c];
#pragma unroll
    for (int reg = 0; reg < 4; ++reg) {
      int rr = r0 + wv * 16 + kgrp * 4 + reg;
      if (rr < NN) h0b[(size_t)rr * 64 + c] = f2bf(2.f * acc[nb][reg] + bias);
    }
  }
}

// ---------------- dense layer 1: MFMA bf16 (K=64, N=32) ----------------

__global__ __launch_bounds__(256) void k_gemm1(const unsigned short* __restrict__ s1b,
                                               const unsigned short* __restrict__ W1bT,
                                               const float* __restrict__ b1,
                                               unsigned short* __restrict__ h1b) {
  __shared__ unsigned short ss[64][72];   // 64 rows x 64 bf16, pad 8
  int t = threadIdx.x;
  int r0 = blockIdx.x * 64;
#pragma unroll
  for (int i = 0; i < 2; ++i) {
    int q = t + i * 256;
    int row = q >> 3;
    int off = q & 7;
    int r = r0 + row;
    uint4 w = make_uint4(0u, 0u, 0u, 0u);
    if (r < NN) w = ((const uint4*)(s1b + (size_t)r * 64))[off];
    *(uint4*)&ss[row][off * 8] = w;
  }
  __syncthreads();

  int lane = t & 63;
  int wv = __builtin_amdgcn_readfirstlane(t >> 6);
  int arow = wv * 16 + (lane & 15);
  int kgrp = lane >> 4;
  int ncol = lane & 15;

  short8 afrag[2];
#pragma unroll
  for (int kb = 0; kb < 2; ++kb)
    afrag[kb] = *(const short8*)&ss[arow][kgrp * 8 + kb * 32];

  short8 bfrag[2][2];
#pragma unroll
  for (int kb = 0; kb < 2; ++kb)
#pragma unroll
    for (int nb = 0; nb < 2; ++nb)
      bfrag[kb][nb] = *(const short8*)&W1bT[(size_t)(nb * 16 + ncol) * 64 +
                                            kgrp * 8 + kb * 32];

  f32x4 acc[2];
#pragma unroll
  for (int nb = 0; nb < 2; ++nb) acc[nb] = (f32x4)(0.f);
#pragma unroll
  for (int kb = 0; kb < 2; ++kb)
#pragma unroll
    for (int nb = 0; nb < 2; ++nb)
      acc[nb] = __builtin_amdgcn_mfma_f32_16x16x32_bf16(afrag[kb], bfrag[kb][nb],
                                                        acc[nb], 0, 0, 0);

#pragma unroll
  for (int nb = 0; nb < 2; ++nb) {
    int c = nb * 16 + ncol;
    float bias = b1[c];
#pragma unroll
    for (int reg = 0; reg < 4; ++reg) {
      int rr = r0 + wv * 16 + kgrp * 4 + reg;
      if (rr < NN) h1b[(size_t)rr * 32 + c] = f2bf(acc[nb][reg] + bias);
    }
  }
}

// ---------------- SpMM (1 row/wave, 32 VGPR, pipelined main + serial tail) ----------------

// D=64: 16 lanes/edge (uint2 = 4 dims), 4 edges/gather-instr, 16 edges in flight.
__global__ __launch_bounds__(256) void k_spmm1(const int* __restrict__ rps,
                                               const int* __restrict__ rpe,
                                               const uint2* __restrict__ vc,
                                               const uint2* __restrict__ h0v,
                                               uint2* __restrict__ s1v) {
  int wid = (blockIdx.x * 256 + threadIdx.x) >> 6;
  int lane = threadIdx.x & 63;
  if (wid >= NN) return;
  int qw = lane >> 4;        // edge slot 0..3
  int d = lane & 15;         // uint2 index: dims 4d..4d+3
  int j0 = rps[wid], j1 = rpe[wid];
  float a0 = 0.f, a1 = 0.f, a2 = 0.f, a3 = 0.f;
  int j = j0 + qw;
  uint2 e0, e1, e2, e3;
  bool have = (j + 12 < j1);
  if (have) { e0 = vc[j]; e1 = vc[j + 4]; e2 = vc[j + 8]; e3 = vc[j + 12]; }
  while (have) {
    uint2 g0 = h0v[(size_t)e0.y * 16 + d];
    uint2 g1 = h0v[(size_t)e1.y * 16 + d];
    uint2 g2 = h0v[(size_t)e2.y * 16 + d];
    uint2 g3 = h0v[(size_t)e3.y * 16 + d];
    float v0 = __uint_as_float(e0.x), v1 = __uint_as_float(e1.x);
    float v2 = __uint_as_float(e2.x), v3 = __uint_as_float(e3.x);
    int jn = j + 16;
    bool hn = (jn + 12 < j1);
    if (hn) { e0 = vc[jn]; e1 = vc[jn + 4]; e2 = vc[jn + 8]; e3 = vc[jn + 12]; }
    a0 = fmaf(v0, lo16(g0.x), a0); a1 = fmaf(v0, hi16(g0.x), a1);
    a2 = fmaf(v0, lo16(g0.y), a2); a3 = fmaf(v0, hi16(g0.y), a3);
    a0 = fmaf(v1, lo16(g1.x), a0); a1 = fmaf(v1, hi16(g1.x), a1);
    a2 = fmaf(v1, lo16(g1.y), a2); a3 = fmaf(v1, hi16(g1.y), a3);
    a0 = fmaf(v2, lo16(g2.x), a0); a1 = fmaf(v2, hi16(g2.x), a1);
    a2 = fmaf(v2, lo16(g2.y), a2); a3 = fmaf(v2, hi16(g2.y), a3);
    a0 = fmaf(v3, lo16(g3.x), a0); a1 = fmaf(v3, hi16(g3.x), a1);
    a2 = fmaf(v3, lo16(g3.y), a2); a3 = fmaf(v3, hi16(g3.y), a3);
    j = jn; have = hn;
  }
  for (; j < j1; j += 4) {
    uint2 e = vc[j];
    uint2 g = h0v[(size_t)e.y * 16 + d];
    float v = __uint_as_float(e.x);
    a0 = fmaf(v, lo16(g.x), a0); a1 = fmaf(v, hi16(g.x), a1);
    a2 = fmaf(v, lo16(g.y), a2); a3 = fmaf(v, hi16(g.y), a3);
  }
  a0 += __shfl_xor(a0, 16); a0 += __shfl_xor(a0, 32);
  a1 += __shfl_xor(a1, 16); a1 += __shfl_xor(a1, 32);
  a2 += __shfl_xor(a2, 16); a2 += __shfl_xor(a2, 32);
  a3 += __shfl_xor(a3, 16); a3 += __shfl_xor(a3, 32);
  if (qw == 0) {
    uint2 pk;
    pk.x = (unsigned int)f2bf(fmaxf(a0, 0.f)) | ((unsigned int)f2bf(fmaxf(a1, 0.f)) << 16);
    pk.y = (unsigned int)f2bf(fmaxf(a2, 0.f)) | ((unsigned int)f2bf(fmaxf(a3, 0.f)) << 16);
    s1v[(size_t)wid * 16 + d] = pk;
  }
}

// D=32: 8 lanes/edge (uint2 = 4 dims), 8 edges/gather-instr, 16 in flight.
__global__ __launch_bounds__(256) void k_spmm2(const int* __restrict__ rps,
                                               const int* __restrict__ rpe,
                                               const uint2* __restrict__ vc,
                                               const uint2* __restrict__ h1v,
                                               float* __restrict__ out) {
  int wid = (blockIdx.x * 256 + threadIdx.x) >> 6;
  int lane = threadIdx.x & 63;
  if (wid >= NN) return;
  int slot = lane >> 3;      // edge slot 0..7
  int d = lane & 7;          // uint2 index: dims 4d..4d+3
  int j0 = rps[wid], j1 = rpe[wid];
  float a0 = 0.f, a1 = 0.f, a2 = 0.f, a3 = 0.f;
  int j = j0 + slot;
  uint2 e0, e1;
  bool have = (j + 8 < j1);
  if (have) { e0 = vc[j]; e1 = vc[j + 8]; }
  while (have) {
    uint2 g0 = h1v[(size_t)e0.y * 8 + d];
    uint2 g1 = h1v[(size_t)e1.y * 8 + d];
    float v0 = __uint_as_float(e0.x), v1 = __uint_as_float(e1.x);
    int jn = j + 16;
    bool hn = (jn + 8 < j1);
    if (hn) { e0 = vc[jn]; e1 = vc[jn + 8]; }
    a0 = fmaf(v0, lo16(g0.x), a0); a1 = fmaf(v0, hi16(g0.x), a1);
    a2 = fmaf(v0, lo16(g0.y), a2); a3 = fmaf(v0, hi16(g0.y), a3);
    a0 = fmaf(v1, lo16(g1.x), a0); a1 = fmaf(v1, hi16(g1.x), a1);
    a2 = fmaf(v1, lo16(g1.y), a2); a3 = fmaf(v1, hi16(g1.y), a3);
    j = jn; have = hn;
  }
  for (; j < j1; j += 8) {
    uint2 e = vc[j];
    uint2 g = h1v[(size_t)e.y * 8 + d];
    float v = __uint_as_float(e.x);
    a0 = fmaf(v, lo16(g.x), a0); a1 = fmaf(v, hi16(g.x), a1);
    a2 = fmaf(v, lo16(g.y), a2); a3 = fmaf(v, hi16(g.y), a3);
  }
  a0 += __shfl_xor(a0, 8); a0 += __shfl_xor(a0, 16); a0 += __shfl_xor(a0, 32);
  a1 += __shfl_xor(a1, 8); a1 += __shfl_xor(a1, 16); a1 += __shfl_xor(a1, 32);
  a2 += __shfl_xor(a2, 8); a2 += __shfl_xor(a2, 16); a2 += __shfl_xor(a2, 32);
  a3 += __shfl_xor(a3, 8); a3 += __shfl_xor(a3, 16); a3 += __shfl_xor(a3, 32);
  if (slot == 0) {
    ((float4*)(out + (size_t)wid * 32))[d] = make_float4(a0, a1, a2, a3);
  }
}

// ---------------- launch ----------------

extern "C" void kernel_launch(void* const* d_in, const int* in_sizes, int n_in,
                              void* d_out, int out_size, void* d_ws, size_t ws_size,
                              hipStream_t stream) {
  const float* x   = (const float*)d_in[0];
  const float* u   = (const float*)d_in[1];
  const float* val = (const float*)d_in[2];
  const int* row   = (const int*)d_in[3];
  const int* col   = (const int*)d_in[4];
  const float* W0  = (const float*)d_in[5];
  const float* b0  = (const float*)d_in[6];
  const float* W1  = (const float*)d_in[7];
  const float* b1  = (const float*)d_in[8];
  float* out = (float*)d_out;

  char* p = (char*)d_ws;
  auto take = [&](size_t bytes) {
    char* q = p;
    p += (bytes + 255) & ~(size_t)255;
    return q;
  };
  uint2* tmp = (uint2*)take((size_t)NBK * CAP * 8);   // dead after k_bsort
  uint2* vc  = (uint2*)take((size_t)NBK * CAP * 8);
  unsigned short* s1b = (unsigned short*)take((size_t)NN * 64 * 2);
  int* rps   = (int*)take((size_t)NN * 4);
  int* rpe   = (int*)take((size_t)NN * 4);
  int* bcur  = (int*)take((size_t)NBK * 4);
  unsigned short* w0bt = (unsigned short*)take((size_t)64 * 128 * 2);
  unsigned short* w1bt = (unsigned short*)take((size_t)32 * 64 * 2);
  // alias h0b (12.8 MB) and h1b (6.4 MB) into tmp's 27.3 MB (tmp dead by gemm0)
  unsigned short* h0b = (unsigned short*)tmp;
  unsigned short* h1b = (unsigned short*)((char*)tmp + (size_t)NN * 64 * 2);

  // CSR build (fixed-window bucket sort; no global histogram needed)
  k_binit<<<1, 256, 0, stream>>>(bcur);
  k_part<<<NBP, 512, 0, stream>>>(row, col, val, bcur, tmp);
  k_bsort<<<NBK, 1024, 0, stream>>>(bcur, tmp, vc, rps, rpe);

  // dense + sparse pipeline
  k_wcvt<<<40, 256, 0, stream>>>(W0, w0bt, W1, w1bt);
  k_gemm0<<<(NN + 63) / 64, 256, 0, stream>>>(x, u, w0bt, b0, h0b);
  k_spmm1<<<(NN + 3) / 4, 256, 0, stream>>>(rps, rpe, vc, (const uint2*)h0b,
                                            (uint2*)s1b);
  k_gemm1<<<(NN + 63) / 64, 256, 0, stream>>>(s1b, w1bt, b1, h1b);
  k_spmm2<<<(NN + 3) / 4, 256, 0, stream>>>(rps, rpe, vc, (const uint2*)h1b, out);
}